// Round 2
// baseline (516.959 us; speedup 1.0000x reference)
//
#include <hip/hip_runtime.h>
#include <hip/hip_bf16.h>

// WindowAttention: B_=4096 windows, N=64 tokens, C=256, H=8 heads, hd=32.
// Fused, persistent: 256 WGs x 1024 threads (16 waves, 4 waves/SIMD), each WG
// loops over 16 windows with register prefetch of the next window's x.
// Head h is split across wave pair (h, h+8). bf16 MFMA, fp32 softmax/output.

typedef __attribute__((ext_vector_type(8))) short bf16x8;   // 8 bf16 = 4 VGPR
typedef __attribute__((ext_vector_type(4))) float f32x4;    // MFMA acc

struct alignas(8) us4 { unsigned short x, y, z, w; };

__device__ inline unsigned short f2bf(float f) {
    unsigned u = __builtin_bit_cast(unsigned, f);
    u += 0x7fffu + ((u >> 16) & 1u);
    return (unsigned short)(u >> 16);
}

__device__ inline f32x4 mfma16(bf16x8 a, bf16x8 b, f32x4 c) {
    return __builtin_amdgcn_mfma_f32_16x16x32_bf16(a, b, c, 0, 0, 0);
}

__device__ inline bf16x8 lds8(const unsigned short* p) {
    return *reinterpret_cast<const bf16x8*>(p);
}

// ---------------- prep: weight casts + dense bias gather --------------------
__global__ void prep_kernel(const float* __restrict__ qkv_w,
                            const float* __restrict__ proj_w,
                            const float* __restrict__ bias_table,
                            const int*   __restrict__ rel_index,
                            unsigned short* __restrict__ qkv_wb,
                            unsigned short* __restrict__ proj_wb,
                            float* __restrict__ biasF) {
    int stride = gridDim.x * blockDim.x;
    int t0 = blockIdx.x * blockDim.x + threadIdx.x;
    for (int i = t0; i < 768 * 256; i += stride) qkv_wb[i] = f2bf(qkv_w[i]);
    for (int i = t0; i < 256 * 256; i += stride) proj_wb[i] = f2bf(proj_w[i]);
    for (int i = t0; i < 8 * 64 * 64; i += stride) {
        int h = i >> 12, rem = i & 4095, m = rem >> 6, n = rem & 63;
        biasF[i] = bias_table[rel_index[m * 64 + n] * 8 + h];
    }
}

// ---------------- fused window attention ------------------------------------
// LDS (ushort units), 76288 us = 152576 B:
//   XB @ 0     : x bf16 [64][264] (16896); reused as attn_out for phase 3
//   QK @ 16896 : per head h (5120): q [64][40] @+0, k [64][40] @+2560
//                (P [64][72] = 4608 overlays q+k after the post-QK^T barrier)
//   VT @ 57856 : per head h (2304): vT [32][72] (v transposed, token-contig)
__global__ __launch_bounds__(1024, 4) void win_attn_kernel(
    const float* __restrict__ x,
    const float* __restrict__ qkv_b,
    const float* __restrict__ proj_b,
    const unsigned short* __restrict__ qkv_wb,
    const unsigned short* __restrict__ proj_wb,
    const float* __restrict__ biasF,
    float* __restrict__ out)
{
    __shared__ unsigned short sm[76288];
    const int tid  = threadIdx.x;
    const int wid  = tid >> 6;         // 0..15
    const int lane = tid & 63;
    const int r16  = lane & 15;
    const int g    = lane >> 4;
    const int h    = wid & 7;          // head
    const int hf   = wid >> 3;         // half: which of the wave pair
    const f32x4 zero4 = {0.f, 0.f, 0.f, 0.f};

    const int qbase = 16896 + h * 5120;
    const int kbase = qbase + 2560;
    const int vtb   = 57856 + h * 2304;

    // wave (h,hf) computes n-tiles: q-tile 2h+hf, k-tile 16+2h+hf, v-tile 32+2h+hf
    const int ntb[3] = { 2 * h + hf, 16 + 2 * h + hf, 32 + 2 * h + hf };

    const int win0 = blockIdx.x * 16;

    // ---- prologue: load + stage x(win0) ----
    float4 pf[4];
#pragma unroll
    for (int i = 0; i < 4; ++i)
        pf[i] = *reinterpret_cast<const float4*>(
            x + (size_t)win0 * 16384 + i * 4096 + tid * 4);
#pragma unroll
    for (int i = 0; i < 4; ++i) {
        int flat = i * 4096 + tid * 4;
        us4 pk = { f2bf(pf[i].x), f2bf(pf[i].y), f2bf(pf[i].z), f2bf(pf[i].w) };
        *reinterpret_cast<us4*>(&sm[(flat >> 8) * 264 + (flat & 255)]) = pk;
    }

    for (int widx = 0; widx < 16; ++widx) {
        const int win = win0 + widx;
        __syncthreads();                                   // B0: XB ready

        // ---- Phase 1: QKV GEMM (wave computes its 3 n-tiles) ----
        f32x4 acc[4][3];
#pragma unroll
        for (int a = 0; a < 4; ++a)
#pragma unroll
            for (int b = 0; b < 3; ++b) acc[a][b] = zero4;

#pragma unroll
        for (int ks = 0; ks < 8; ++ks) {
            bf16x8 af[4];
#pragma unroll
            for (int mt = 0; mt < 4; ++mt)
                af[mt] = lds8(&sm[(mt * 16 + r16) * 264 + ks * 32 + g * 8]);
#pragma unroll
            for (int ni = 0; ni < 3; ++ni) {
                bf16x8 bf = *reinterpret_cast<const bf16x8*>(
                    qkv_wb + (ntb[ni] * 16 + r16) * 256 + ks * 32 + g * 8);
#pragma unroll
                for (int mt = 0; mt < 4; ++mt)
                    acc[mt][ni] = mfma16(af[mt], bf, acc[mt][ni]);
            }
        }

        const int d = hf * 16 + r16;     // channel within head [0,32)
#pragma unroll
        for (int ni = 0; ni < 3; ++ni) {
            float qb = qkv_b[ntb[ni] * 16 + r16];
#pragma unroll
            for (int mt = 0; mt < 4; ++mt) {
                f32x4 a4 = acc[mt][ni];
                if (ni == 0) {
#pragma unroll
                    for (int j = 0; j < 4; ++j)
                        sm[qbase + (mt * 16 + g * 4 + j) * 40 + d] = f2bf(a4[j] + qb);
                } else if (ni == 1) {
#pragma unroll
                    for (int j = 0; j < 4; ++j)
                        sm[kbase + (mt * 16 + g * 4 + j) * 40 + d] = f2bf(a4[j] + qb);
                } else {
                    us4 pk = { f2bf(a4[0] + qb), f2bf(a4[1] + qb),
                               f2bf(a4[2] + qb), f2bf(a4[3] + qb) };
                    *reinterpret_cast<us4*>(&sm[vtb + d * 72 + mt * 16 + g * 4]) = pk;
                }
            }
        }
        __syncthreads();                                   // B1: q/k/v ready, xb reads done

        // prefetch next window's x (latency hidden under phases 2+3)
        if (widx < 15) {
#pragma unroll
            for (int i = 0; i < 4; ++i)
                pf[i] = *reinterpret_cast<const float4*>(
                    x + (size_t)(win + 1) * 16384 + i * 4096 + tid * 4);
        }

        // ---- Phase 2: attention. Swapped QK^T: S^T = K·Q^T ----
        bf16x8 ak[4], bq[2];
#pragma unroll
        for (int t = 0; t < 4; ++t)
            ak[t] = lds8(&sm[kbase + (t * 16 + r16) * 40 + g * 8]);
#pragma unroll
        for (int c = 0; c < 2; ++c)
            bq[c] = lds8(&sm[qbase + ((2 * hf + c) * 16 + r16) * 40 + g * 8]);

        f32x4 st[4][2];
#pragma unroll
        for (int rt = 0; rt < 4; ++rt)
#pragma unroll
            for (int c = 0; c < 2; ++c)
                st[rt][c] = mfma16(ak[rt], bq[c], zero4);
        __syncthreads();                 // B2a: all q/k reads done before P overlays

        const float scale = 0.1767766952966369f;   // 1/sqrt(32)
        const float* bh = biasF + h * 4096;

#pragma unroll
        for (int c = 0; c < 2; ++c) {
            int m = (2 * hf + c) * 16 + r16;       // query row (wave-owned)
            float pv[4][4];
            float mx = -1e30f;
#pragma unroll
            for (int rt = 0; rt < 4; ++rt) {
                float4 b4 = *reinterpret_cast<const float4*>(
                    bh + m * 64 + rt * 16 + g * 4);
                float bb[4] = { b4.x, b4.y, b4.z, b4.w };
#pragma unroll
                for (int j = 0; j < 4; ++j) {
                    float v = st[rt][c][j] * scale + bb[j];
                    pv[rt][j] = v;
                    mx = fmaxf(mx, v);
                }
            }
            mx = fmaxf(mx, __shfl_xor(mx, 16));
            mx = fmaxf(mx, __shfl_xor(mx, 32));
            float s = 0.f;
#pragma unroll
            for (int rt = 0; rt < 4; ++rt)
#pragma unroll
                for (int j = 0; j < 4; ++j) {
                    float e = __expf(pv[rt][j] - mx);
                    pv[rt][j] = e;
                    s += e;
                }
            s += __shfl_xor(s, 16);
            s += __shfl_xor(s, 32);
            float inv = 1.f / s;
#pragma unroll
            for (int rt = 0; rt < 4; ++rt) {
                us4 pk = { f2bf(pv[rt][0] * inv), f2bf(pv[rt][1] * inv),
                           f2bf(pv[rt][2] * inv), f2bf(pv[rt][3] * inv) };
                *reinterpret_cast<us4*>(&sm[qbase + m * 72 + rt * 16 + g * 4]) = pk;
            }
        }
        // P rows a wave wrote are exactly the rows its PV reads (wave-local).
        asm volatile("s_waitcnt lgkmcnt(0)" ::: "memory");

        // PV: out_h[rows 32hf..32hf+32][32] = P · v_h
        f32x4 o[2][2];
#pragma unroll
        for (int a = 0; a < 2; ++a)
#pragma unroll
            for (int b = 0; b < 2; ++b) o[a][b] = zero4;
#pragma unroll
        for (int ks = 0; ks < 2; ++ks) {
            bf16x8 ap[2];
#pragma unroll
            for (int mtl = 0; mtl < 2; ++mtl)
                ap[mtl] = lds8(&sm[qbase + ((2 * hf + mtl) * 16 + r16) * 72
                                   + ks * 32 + g * 8]);
#pragma unroll
            for (int nt = 0; nt < 2; ++nt) {
                bf16x8 bv = lds8(&sm[vtb + (nt * 16 + r16) * 72 + ks * 32 + g * 8]);
#pragma unroll
                for (int mtl = 0; mtl < 2; ++mtl)
                    o[mtl][nt] = mfma16(ap[mtl], bv, o[mtl][nt]);
            }
        }
#pragma unroll
        for (int mtl = 0; mtl < 2; ++mtl)
#pragma unroll
            for (int nt = 0; nt < 2; ++nt)
#pragma unroll
                for (int j = 0; j < 4; ++j)
                    sm[((2 * hf + mtl) * 16 + g * 4 + j) * 264
                       + h * 32 + nt * 16 + r16] = f2bf(o[mtl][nt][j]);
        __syncthreads();                                   // B2b: attn_out ready

        // ---- Phase 3: proj GEMM, wave w owns output cols [16w, 16w+16) ----
        f32x4 c3[4];
#pragma unroll
        for (int mt = 0; mt < 4; ++mt) c3[mt] = zero4;
#pragma unroll
        for (int ks = 0; ks < 8; ++ks) {
            bf16x8 b3 = *reinterpret_cast<const bf16x8*>(
                proj_wb + (wid * 16 + r16) * 256 + ks * 32 + g * 8);
#pragma unroll
            for (int mt = 0; mt < 4; ++mt) {
                bf16x8 a3 = lds8(&sm[(mt * 16 + r16) * 264 + ks * 32 + g * 8]);
                c3[mt] = mfma16(a3, b3, c3[mt]);
            }
        }
        __syncthreads();                                   // B3: attn_out reads done

        float* og = out + (size_t)win * 16384;
        {
            int n = wid * 16 + r16;
            float pb = proj_b[n];
#pragma unroll
            for (int mt = 0; mt < 4; ++mt)
#pragma unroll
                for (int j = 0; j < 4; ++j)
                    og[(size_t)(mt * 16 + g * 4 + j) * 256 + n] = c3[mt][j] + pb;
        }

        // stage prefetched x(win+1) into XB (safe: attn_out reads drained at B3)
        if (widx < 15) {
#pragma unroll
            for (int i = 0; i < 4; ++i) {
                int flat = i * 4096 + tid * 4;
                us4 pk = { f2bf(pf[i].x), f2bf(pf[i].y),
                           f2bf(pf[i].z), f2bf(pf[i].w) };
                *reinterpret_cast<us4*>(&sm[(flat >> 8) * 264 + (flat & 255)]) = pk;
            }
        }
    }
}

extern "C" void kernel_launch(void* const* d_in, const int* in_sizes, int n_in,
                              void* d_out, int out_size, void* d_ws, size_t ws_size,
                              hipStream_t stream) {
    const float* x          = (const float*)d_in[0];
    const float* qkv_w      = (const float*)d_in[1];
    const float* qkv_b      = (const float*)d_in[2];
    const float* proj_w     = (const float*)d_in[3];
    const float* proj_b     = (const float*)d_in[4];
    const float* bias_table = (const float*)d_in[5];
    const int*   rel_index  = (const int*)d_in[6];

    unsigned short* qkv_wb  = (unsigned short*)d_ws;
    unsigned short* proj_wb = (unsigned short*)((char*)d_ws + 393216);
    float* biasF            = (float*)((char*)d_ws + 524288);

    prep_kernel<<<256, 256, 0, stream>>>(qkv_w, proj_w, bias_table, rel_index,
                                         qkv_wb, proj_wb, biasF);
    win_attn_kernel<<<256, 1024, 0, stream>>>(x, qkv_b, proj_b, qkv_wb, proj_wb,
                                              biasF, (float*)d_out);
}

// Round 3
// 514.805 us; speedup vs baseline: 1.0042x; 1.0042x over previous
//
#include <hip/hip_runtime.h>
#include <hip/hip_bf16.h>

// WindowAttention: B_=4096 windows, N=64 tokens, C=256, H=8 heads, hd=32.
// Fused, persistent: 256 WGs x 1024 threads (16 waves, 4 waves/SIMD), each WG
// loops over 16 windows with register prefetch of the next window's x.
// Head h is split across wave pair (h, h+8). bf16 MFMA, fp32 softmax/output.
// amdgpu_waves_per_eu(4,4) pins the VGPR budget at 128 (r2's launch_bounds
// gave 64 -> massive scratch spills, FETCH 209MB -> 1.14GB).

typedef __attribute__((ext_vector_type(8))) short bf16x8;   // 8 bf16 = 4 VGPR
typedef __attribute__((ext_vector_type(4))) float f32x4;    // MFMA acc

struct alignas(8) us4 { unsigned short x, y, z, w; };

__device__ inline unsigned short f2bf(float f) {
    unsigned u = __builtin_bit_cast(unsigned, f);
    u += 0x7fffu + ((u >> 16) & 1u);
    return (unsigned short)(u >> 16);
}

__device__ inline f32x4 mfma16(bf16x8 a, bf16x8 b, f32x4 c) {
    return __builtin_amdgcn_mfma_f32_16x16x32_bf16(a, b, c, 0, 0, 0);
}

__device__ inline bf16x8 lds8(const unsigned short* p) {
    return *reinterpret_cast<const bf16x8*>(p);
}

// ---------------- prep: weight casts + dense bias gather --------------------
__global__ void prep_kernel(const float* __restrict__ qkv_w,
                            const float* __restrict__ proj_w,
                            const float* __restrict__ bias_table,
                            const int*   __restrict__ rel_index,
                            unsigned short* __restrict__ qkv_wb,
                            unsigned short* __restrict__ proj_wb,
                            float* __restrict__ biasF) {
    int stride = gridDim.x * blockDim.x;
    int t0 = blockIdx.x * blockDim.x + threadIdx.x;
    for (int i = t0; i < 768 * 256; i += stride) qkv_wb[i] = f2bf(qkv_w[i]);
    for (int i = t0; i < 256 * 256; i += stride) proj_wb[i] = f2bf(proj_w[i]);
    for (int i = t0; i < 8 * 64 * 64; i += stride) {
        int h = i >> 12, rem = i & 4095, m = rem >> 6, n = rem & 63;
        biasF[i] = bias_table[rel_index[m * 64 + n] * 8 + h];
    }
}

// ---------------- fused window attention ------------------------------------
// LDS (ushort units), 76288 us = 152576 B:
//   XB @ 0     : x bf16 [64][264] (16896); reused as attn_out for phase 3
//   QK @ 16896 : per head h (5120): q [64][40] @+0, k [64][40] @+2560
//                (P [64][72] = 4608 overlays q+k after the post-QK^T barrier)
//   VT @ 57856 : per head h (2304): vT [32][72] (v transposed, token-contig)
__global__
__attribute__((amdgpu_flat_work_group_size(1024, 1024), amdgpu_waves_per_eu(4, 4)))
void win_attn_kernel(
    const float* __restrict__ x,
    const float* __restrict__ qkv_b,
    const float* __restrict__ proj_b,
    const unsigned short* __restrict__ qkv_wb,
    const unsigned short* __restrict__ proj_wb,
    const float* __restrict__ biasF,
    float* __restrict__ out)
{
    __shared__ unsigned short sm[76288];
    const int tid  = threadIdx.x;
    const int wid  = tid >> 6;         // 0..15
    const int lane = tid & 63;
    const int r16  = lane & 15;
    const int g    = lane >> 4;
    const int h    = wid & 7;          // head
    const int hf   = wid >> 3;         // half: which of the wave pair
    const f32x4 zero4 = {0.f, 0.f, 0.f, 0.f};

    const int qbase = 16896 + h * 5120;
    const int kbase = qbase + 2560;
    const int vtb   = 57856 + h * 2304;

    // wave (h,hf) computes n-tiles: q-tile 2h+hf, k-tile 16+2h+hf, v-tile 32+2h+hf
    const int ntb[3] = { 2 * h + hf, 16 + 2 * h + hf, 32 + 2 * h + hf };

    const int win0 = blockIdx.x * 16;

    // ---- prologue: load + stage x(win0) ----
    float4 pf[4];
#pragma unroll
    for (int i = 0; i < 4; ++i)
        pf[i] = *reinterpret_cast<const float4*>(
            x + (size_t)win0 * 16384 + i * 4096 + tid * 4);
#pragma unroll
    for (int i = 0; i < 4; ++i) {
        int flat = i * 4096 + tid * 4;
        us4 pk = { f2bf(pf[i].x), f2bf(pf[i].y), f2bf(pf[i].z), f2bf(pf[i].w) };
        *reinterpret_cast<us4*>(&sm[(flat >> 8) * 264 + (flat & 255)]) = pk;
    }

    for (int widx = 0; widx < 16; ++widx) {
        const int win = win0 + widx;
        __syncthreads();                                   // B0: XB ready

        // ---- Phase 1: QKV GEMM (wave computes its 3 n-tiles) ----
        f32x4 acc[4][3];
#pragma unroll
        for (int a = 0; a < 4; ++a)
#pragma unroll
            for (int b = 0; b < 3; ++b) acc[a][b] = zero4;

#pragma unroll
        for (int ks = 0; ks < 8; ++ks) {
            bf16x8 af[4];
#pragma unroll
            for (int mt = 0; mt < 4; ++mt)
                af[mt] = lds8(&sm[(mt * 16 + r16) * 264 + ks * 32 + g * 8]);
#pragma unroll
            for (int ni = 0; ni < 3; ++ni) {
                bf16x8 bf = *reinterpret_cast<const bf16x8*>(
                    qkv_wb + (ntb[ni] * 16 + r16) * 256 + ks * 32 + g * 8);
#pragma unroll
                for (int mt = 0; mt < 4; ++mt)
                    acc[mt][ni] = mfma16(af[mt], bf, acc[mt][ni]);
            }
        }

        const int d = hf * 16 + r16;     // channel within head [0,32)
#pragma unroll
        for (int ni = 0; ni < 3; ++ni) {
            float qb = qkv_b[ntb[ni] * 16 + r16];
#pragma unroll
            for (int mt = 0; mt < 4; ++mt) {
                f32x4 a4 = acc[mt][ni];
                if (ni == 0) {
#pragma unroll
                    for (int j = 0; j < 4; ++j)
                        sm[qbase + (mt * 16 + g * 4 + j) * 40 + d] = f2bf(a4[j] + qb);
                } else if (ni == 1) {
#pragma unroll
                    for (int j = 0; j < 4; ++j)
                        sm[kbase + (mt * 16 + g * 4 + j) * 40 + d] = f2bf(a4[j] + qb);
                } else {
                    us4 pk = { f2bf(a4[0] + qb), f2bf(a4[1] + qb),
                               f2bf(a4[2] + qb), f2bf(a4[3] + qb) };
                    *reinterpret_cast<us4*>(&sm[vtb + d * 72 + mt * 16 + g * 4]) = pk;
                }
            }
        }
        __syncthreads();                                   // B1: q/k/v ready, xb reads done

        // prefetch next window's x (latency hidden under phases 2+3)
        if (widx < 15) {
#pragma unroll
            for (int i = 0; i < 4; ++i)
                pf[i] = *reinterpret_cast<const float4*>(
                    x + (size_t)(win + 1) * 16384 + i * 4096 + tid * 4);
        }

        // ---- Phase 2: attention. Swapped QK^T: S^T = K·Q^T ----
        bf16x8 ak[4], bq[2];
#pragma unroll
        for (int t = 0; t < 4; ++t)
            ak[t] = lds8(&sm[kbase + (t * 16 + r16) * 40 + g * 8]);
#pragma unroll
        for (int c = 0; c < 2; ++c)
            bq[c] = lds8(&sm[qbase + ((2 * hf + c) * 16 + r16) * 40 + g * 8]);

        f32x4 st[4][2];
#pragma unroll
        for (int rt = 0; rt < 4; ++rt)
#pragma unroll
            for (int c = 0; c < 2; ++c)
                st[rt][c] = mfma16(ak[rt], bq[c], zero4);
        __syncthreads();                 // B2a: all q/k reads done before P overlays

        const float scale = 0.1767766952966369f;   // 1/sqrt(32)
        const float* bh = biasF + h * 4096;

#pragma unroll
        for (int c = 0; c < 2; ++c) {
            int m = (2 * hf + c) * 16 + r16;       // query row (wave-owned)
            float pv[4][4];
            float mx = -1e30f;
#pragma unroll
            for (int rt = 0; rt < 4; ++rt) {
                float4 b4 = *reinterpret_cast<const float4*>(
                    bh + m * 64 + rt * 16 + g * 4);
                float bb[4] = { b4.x, b4.y, b4.z, b4.w };
#pragma unroll
                for (int j = 0; j < 4; ++j) {
                    float v = st[rt][c][j] * scale + bb[j];
                    pv[rt][j] = v;
                    mx = fmaxf(mx, v);
                }
            }
            mx = fmaxf(mx, __shfl_xor(mx, 16));
            mx = fmaxf(mx, __shfl_xor(mx, 32));
            float s = 0.f;
#pragma unroll
            for (int rt = 0; rt < 4; ++rt)
#pragma unroll
                for (int j = 0; j < 4; ++j) {
                    float e = __expf(pv[rt][j] - mx);
                    pv[rt][j] = e;
                    s += e;
                }
            s += __shfl_xor(s, 16);
            s += __shfl_xor(s, 32);
            float inv = 1.f / s;
#pragma unroll
            for (int rt = 0; rt < 4; ++rt) {
                us4 pk = { f2bf(pv[rt][0] * inv), f2bf(pv[rt][1] * inv),
                           f2bf(pv[rt][2] * inv), f2bf(pv[rt][3] * inv) };
                *reinterpret_cast<us4*>(&sm[qbase + m * 72 + rt * 16 + g * 4]) = pk;
            }
        }
        // P rows a wave wrote are exactly the rows its PV reads (wave-local).
        asm volatile("s_waitcnt lgkmcnt(0)" ::: "memory");

        // PV: out_h[rows 32hf..32hf+32][32] = P · v_h
        f32x4 o[2][2];
#pragma unroll
        for (int a = 0; a < 2; ++a)
#pragma unroll
            for (int b = 0; b < 2; ++b) o[a][b] = zero4;
#pragma unroll
        for (int ks = 0; ks < 2; ++ks) {
            bf16x8 ap[2];
#pragma unroll
            for (int mtl = 0; mtl < 2; ++mtl)
                ap[mtl] = lds8(&sm[qbase + ((2 * hf + mtl) * 16 + r16) * 72
                                   + ks * 32 + g * 8]);
#pragma unroll
            for (int nt = 0; nt < 2; ++nt) {
                bf16x8 bv = lds8(&sm[vtb + (nt * 16 + r16) * 72 + ks * 32 + g * 8]);
#pragma unroll
                for (int mtl = 0; mtl < 2; ++mtl)
                    o[mtl][nt] = mfma16(ap[mtl], bv, o[mtl][nt]);
            }
        }
#pragma unroll
        for (int mtl = 0; mtl < 2; ++mtl)
#pragma unroll
            for (int nt = 0; nt < 2; ++nt)
#pragma unroll
                for (int j = 0; j < 4; ++j)
                    sm[((2 * hf + mtl) * 16 + g * 4 + j) * 264
                       + h * 32 + nt * 16 + r16] = f2bf(o[mtl][nt][j]);
        __syncthreads();                                   // B2b: attn_out ready

        // ---- Phase 3: proj GEMM, wave w owns output cols [16w, 16w+16) ----
        f32x4 c3[4];
#pragma unroll
        for (int mt = 0; mt < 4; ++mt) c3[mt] = zero4;
#pragma unroll
        for (int ks = 0; ks < 8; ++ks) {
            bf16x8 b3 = *reinterpret_cast<const bf16x8*>(
                proj_wb + (wid * 16 + r16) * 256 + ks * 32 + g * 8);
#pragma unroll
            for (int mt = 0; mt < 4; ++mt) {
                bf16x8 a3 = lds8(&sm[(mt * 16 + r16) * 264 + ks * 32 + g * 8]);
                c3[mt] = mfma16(a3, b3, c3[mt]);
            }
        }
        __syncthreads();                                   // B3: attn_out reads done

        float* og = out + (size_t)win * 16384;
        {
            int n = wid * 16 + r16;
            float pb = proj_b[n];
#pragma unroll
            for (int mt = 0; mt < 4; ++mt)
#pragma unroll
                for (int j = 0; j < 4; ++j)
                    og[(size_t)(mt * 16 + g * 4 + j) * 256 + n] = c3[mt][j] + pb;
        }

        // stage prefetched x(win+1) into XB (safe: attn_out reads drained at B3)
        if (widx < 15) {
#pragma unroll
            for (int i = 0; i < 4; ++i) {
                int flat = i * 4096 + tid * 4;
                us4 pk = { f2bf(pf[i].x), f2bf(pf[i].y),
                           f2bf(pf[i].z), f2bf(pf[i].w) };
                *reinterpret_cast<us4*>(&sm[(flat >> 8) * 264 + (flat & 255)]) = pk;
            }
        }
    }
}

extern "C" void kernel_launch(void* const* d_in, const int* in_sizes, int n_in,
                              void* d_out, int out_size, void* d_ws, size_t ws_size,
                              hipStream_t stream) {
    const float* x          = (const float*)d_in[0];
    const float* qkv_w      = (const float*)d_in[1];
    const float* qkv_b      = (const float*)d_in[2];
    const float* proj_w     = (const float*)d_in[3];
    const float* proj_b     = (const float*)d_in[4];
    const float* bias_table = (const float*)d_in[5];
    const int*   rel_index  = (const int*)d_in[6];

    unsigned short* qkv_wb  = (unsigned short*)d_ws;
    unsigned short* proj_wb = (unsigned short*)((char*)d_ws + 393216);
    float* biasF            = (float*)((char*)d_ws + 524288);

    prep_kernel<<<256, 256, 0, stream>>>(qkv_w, proj_w, bias_table, rel_index,
                                         qkv_wb, proj_wb, biasF);
    win_attn_kernel<<<256, 1024, 0, stream>>>(x, qkv_b, proj_b, qkv_wb, proj_wb,
                                              biasF, (float*)d_out);
}